// Round 16
// baseline (172.320 us; speedup 1.0000x reference)
//
#include <hip/hip_runtime.h>
#include <hip/hip_bf16.h>
#include <stdint.h>

#define B_N 2
#define S_N 2048
#define D_N 1024
#define H_N 16
#define LOG2E 1.44269504f

using bf8    = __attribute__((ext_vector_type(8))) short;   // 8 bf16 (4 VGPRs)
using us8    = __attribute__((ext_vector_type(8))) unsigned short;
using f32x4  = __attribute__((ext_vector_type(4))) float;
using f32x16 = __attribute__((ext_vector_type(16))) float;

static __device__ __forceinline__ ushort f2b(float f) {
  uint32_t u = __builtin_bit_cast(uint32_t, f);
  u += 0x7fffu + ((u >> 16) & 1u);     // RNE
  return (ushort)(u >> 16);
}

static __device__ __forceinline__ uint32_t cvtpk(float a, float b) {
  uint32_t r;
  asm("v_cvt_pk_bf16_f32 %0, %1, %2" : "=v"(r) : "v"(a), "v"(b));
  return r;   // low = a, high = b
}

static __device__ __forceinline__ float h2f(ushort u) {
  return (float)__builtin_bit_cast(_Float16, u);
}

static __device__ __forceinline__ ushort h16(float x) {
  return __builtin_bit_cast(ushort, (_Float16)x);
}

typedef __attribute__((address_space(1))) const uint32_t GU32;
typedef __attribute__((address_space(3))) uint32_t LU32;
static __device__ __forceinline__ void gload16(const void* g, void* l) {
  __builtin_amdgcn_global_load_lds((GU32*)g, (LU32*)l, 16, 0, 0);
}

static __device__ __forceinline__ void cvt4B(const float* __restrict__ s, ushort* __restrict__ d, int i) {
  float4 v = *(const float4*)(s + i);
  ushort4 o;
  o.x = f2b(v.x); o.y = f2b(v.y); o.z = f2b(v.z); o.w = f2b(v.w);
  *(ushort4*)(d + i) = o;
}

// ---------------- fused prep: f32->bf16 converts + code packing ----------------
__global__ __launch_bounds__(256) void prep_kernel(
    const float* __restrict__ q, const float* __restrict__ k, const float* __restrict__ v,
    const float* __restrict__ wq, const float* __restrict__ wk, const float* __restrict__ wv,
    const float* __restrict__ wo,
    ushort* __restrict__ oq, ushort* __restrict__ ok, ushort* __restrict__ ov,
    ushort* __restrict__ owq, ushort* __restrict__ owk, ushort* __restrict__ owv,
    ushort* __restrict__ owo,
    const int* __restrict__ f, const int* __restrict__ e, const int* __restrict__ ti,
    const int* __restrict__ tt, const int* __restrict__ ed, const int* __restrict__ ro,
    uint32_t* __restrict__ codes) {
  int x = blockIdx.x;
  if (x < 12288) {
    int which = x >> 12, i = (x & 4095) * 1024 + threadIdx.x * 4;
    const float* s = (which == 0) ? q : (which == 1) ? k : v;
    ushort* d = (which == 0) ? oq : (which == 1) ? ok : ov;
    cvt4B(s, d, i);
  } else if (x < 16384) {
    int which = (x - 12288) >> 10, i = (x & 1023) * 1024 + threadIdx.x * 4;
    const float* s = (which == 0) ? wq : (which == 1) ? wk : (which == 2) ? wv : wo;
    ushort* d = (which == 0) ? owq : (which == 1) ? owk : (which == 2) ? owv : owo;
    cvt4B(s, d, i);
  } else {
    int i = (x - 16384) * 256 + threadIdx.x;
    uint32_t c = ((uint32_t)f[i] & 31u) | (((uint32_t)e[i] & 63u) << 5) |
                 (((uint32_t)ti[i] & 127u) << 11) | (((uint32_t)tt[i] & 7u) << 18) |
                 (((uint32_t)ro[i] & 7u) << 21) |
                 ((ed[i] != 0) ? (1u << 24) : 0u) | ((f[i] == 0) ? (1u << 25) : 0u);
    codes[i] = c;
  }
}

static __device__ __forceinline__ float bias_val(uint32_t a, uint32_t b) {
  uint32_t x = a ^ b;
  uint32_t o = a | b;
  float v = (o & 0x1000000u) ? 1.5f : 0.0f;   // has_edge
  v += (x & 0x1Fu)     ? 0.0f : 1.0f;          // field
  v += (x & 0x7E0u)    ? 0.0f : 1.0f;          // entity
  v += (x & 0x3F800u)  ? 0.0f : 0.5f;          // time
  v += (x & 0x1C0000u) ? 0.0f : 0.3f;          // token_type
  v += (x & 0xE00000u) ? 0.0f : 0.5f;          // role
  return (o & 0x2000000u) ? -30000.f : v;      // pad -> big negative
}

// Fragment-major fp16 bias, log2e-scaled (no shift needed: softmax cancels constants).
__global__ __launch_bounds__(256) void bias_build(const uint32_t* __restrict__ codes,
                                                  ushort* __restrict__ BF) {
  int t = blockIdx.x * 256 + threadIdx.x;      // 0 .. 2^20-1
  int v8    = t & 1;
  int lane  = (t >> 1) & 63;
  int h     = (t >> 7) & 1;
  int kvt   = (t >> 8) & 31;
  int qtile = (t >> 13) & 63;
  int b     = t >> 19;
  int hi = lane >> 5;
  int q  = qtile * 32 + (lane & 31);
  uint32_t cq = codes[b * S_N + q];
  int kvb = kvt * 64 + h * 32 + v8 * 16 + hi * 4;
  uint4 c0 = *(const uint4*)(codes + b * S_N + kvb);
  uint4 c1 = *(const uint4*)(codes + b * S_N + kvb + 8);
  ushort o[8];
  o[0] = h16(bias_val(cq, c0.x) * LOG2E);
  o[1] = h16(bias_val(cq, c0.y) * LOG2E);
  o[2] = h16(bias_val(cq, c0.z) * LOG2E);
  o[3] = h16(bias_val(cq, c0.w) * LOG2E);
  o[4] = h16(bias_val(cq, c1.x) * LOG2E);
  o[5] = h16(bias_val(cq, c1.y) * LOG2E);
  o[6] = h16(bias_val(cq, c1.z) * LOG2E);
  o[7] = h16(bias_val(cq, c1.w) * LOG2E);
  *(uint4*)(BF + (size_t)t * 8) = *(const uint4*)o;
}

// ---------------- GEMM core: C[M,N] = A[M,K] @ W[N,K]^T + bias ----------------
// MODE 0: Q fragment-major; MODE 3: K fragment-major; MODE 2: V fragment-major.
template <int MODE>
static __device__ __forceinline__ void gemm_core(ushort* As, ushort* Bs,
    const ushort* __restrict__ A, const ushort* __restrict__ W, const float* __restrict__ bias,
    void* __restrict__ out, float scale) {
  const int tid = threadIdx.x, lane = tid & 63, wid = tid >> 6;
  const int g = lane >> 4, c = lane & 15;
  const int wm = wid >> 1, wn = wid & 1;
  const int m0 = blockIdx.y * 128, n0 = blockIdx.x * 128;

  f32x4 acc[4][4];
#pragma unroll
  for (int i = 0; i < 4; ++i)
#pragma unroll
    for (int j = 0; j < 4; ++j) acc[i][j] = (f32x4){0.f, 0.f, 0.f, 0.f};

  for (int k0 = 0; k0 < D_N; k0 += 32) {
#pragma unroll
    for (int j = 0; j < 2; ++j) {
      int idx = tid + j * 256;                  // 0..511
      int row = idx >> 2, c8 = (idx & 3) * 8;
      gload16(A + (size_t)(m0 + row) * D_N + k0 + c8, As + idx * 8);
      gload16(W + (size_t)(n0 + row) * D_N + k0 + c8, Bs + idx * 8);
    }
    __syncthreads();
    bf8 af[4], bw[4];
#pragma unroll
    for (int mi = 0; mi < 4; ++mi) af[mi] = *(const bf8*)(As + (wm * 64 + mi * 16 + c) * 32 + g * 8);
#pragma unroll
    for (int ni = 0; ni < 4; ++ni) bw[ni] = *(const bf8*)(Bs + (wn * 64 + ni * 16 + c) * 32 + g * 8);
#pragma unroll
    for (int mi = 0; mi < 4; ++mi)
#pragma unroll
      for (int ni = 0; ni < 4; ++ni)
        acc[mi][ni] = __builtin_amdgcn_mfma_f32_16x16x32_bf16(af[mi], bw[ni], acc[mi][ni], 0, 0, 0);
    __syncthreads();
  }

#pragma unroll
  for (int mi = 0; mi < 4; ++mi)
#pragma unroll
    for (int ni = 0; ni < 4; ++ni) {
      int ncol = n0 + wn * 64 + ni * 16 + c;
      float bv = bias[ncol];
      int hh = ncol >> 6, dd = ncol & 63;
      if (MODE == 2) {
        int mb = m0 + wm * 64 + mi * 16 + g * 4;
        int bb = mb >> 11, kv = mb & 2047;
        int kvt = kv >> 6, kin = kv & 63;
        int ks = kin >> 4, hif = (kin >> 3) & 1, e = kin & 7;
        int jj = dd >> 5, l31v = dd & 31;
        int lanef = hif * 32 + l31v;
        size_t off = (((size_t)(bb * H_N + hh) * 32 + kvt) * 8 + ks * 2 + jj) * 512 + lanef * 8 + e;
        ushort4 o4;
        o4.x = f2b((acc[mi][ni][0] + bv) * scale);
        o4.y = f2b((acc[mi][ni][1] + bv) * scale);
        o4.z = f2b((acc[mi][ni][2] + bv) * scale);
        o4.w = f2b((acc[mi][ni][3] + bv) * scale);
        *(ushort4*)((ushort*)out + off) = o4;
      } else {
#pragma unroll
        for (int r = 0; r < 4; ++r) {
          int m = m0 + wm * 64 + mi * 16 + g * 4 + r;
          float v = (acc[mi][ni][r] + bv) * scale;
          if (MODE == 0) {
            int bb = m >> 11, q = m & 2047;
            int qtile = q >> 5, l31q = q & 31;
            int ks = dd >> 4, hif = (dd >> 3) & 1, e = dd & 7;
            int lanef = hif * 32 + l31q;
            size_t off = (((size_t)(bb * H_N + hh) * 64 + qtile) * 4 + ks) * 512 + lanef * 8 + e;
            ((ushort*)out)[off] = f2b(v);
          } else {
            int bb = m >> 11, s = m & 2047;
            int kvt = s >> 6, sin = s & 63;
            int jj = sin >> 5, l31k = sin & 31;
            int ks = dd >> 4, hif = (dd >> 3) & 1, e = dd & 7;
            int lanef = hif * 32 + l31k;
            size_t off = (((size_t)(bb * H_N + hh) * 32 + kvt) * 8 + ks * 2 + jj) * 512 + lanef * 8 + e;
            ((ushort*)out)[off] = f2b(v);
          }
        }
      }
    }
}

__global__ __launch_bounds__(256) void gemm_qkv(
    const ushort* __restrict__ Xq, const ushort* __restrict__ Xk, const ushort* __restrict__ Xv,
    const ushort* __restrict__ Wq, const ushort* __restrict__ Wk, const ushort* __restrict__ Wv,
    const float* __restrict__ bq, const float* __restrict__ bk, const float* __restrict__ bv,
    ushort* __restrict__ Qo, ushort* __restrict__ Ko, ushort* __restrict__ Vo) {
  __shared__ __align__(16) ushort As[128 * 32];
  __shared__ __align__(16) ushort Bs[128 * 32];
  // Q carries 1/sqrt(64) * log2(e) so softmax runs in exp2 domain
  if (blockIdx.z == 0)      gemm_core<0>(As, Bs, Xq, Wq, bq, Qo, 0.125f * LOG2E);
  else if (blockIdx.z == 1) gemm_core<3>(As, Bs, Xk, Wk, bk, Ko, 1.0f);
  else                      gemm_core<2>(As, Bs, Xv, Wv, bv, Vo, 1.0f);
}

// gemm_o: 64x128 tiles -> grid (8, 64) = 512 blocks = 2 blocks/CU (vs 1 at 128x128).
// 4 waves side-by-side in N (wn = wid), each 64x32 output.
__global__ __launch_bounds__(256) void gemm_o(const ushort* __restrict__ A, const ushort* __restrict__ W,
                                              const float* __restrict__ bias, float* __restrict__ out) {
  __shared__ __align__(16) ushort As[64 * 32];
  __shared__ __align__(16) ushort Bs[128 * 32];
  const int tid = threadIdx.x, lane = tid & 63, wn = tid >> 6;
  const int g = lane >> 4, c = lane & 15;
  const int m0 = blockIdx.y * 64, n0 = blockIdx.x * 128;

  f32x4 acc[4][2];
#pragma unroll
  for (int i = 0; i < 4; ++i)
#pragma unroll
    for (int j = 0; j < 2; ++j) acc[i][j] = (f32x4){0.f, 0.f, 0.f, 0.f};

  for (int k0 = 0; k0 < D_N; k0 += 32) {
    {
      int row = tid >> 2, c8 = (tid & 3) * 8;
      gload16(A + (size_t)(m0 + row) * D_N + k0 + c8, As + tid * 8);
    }
#pragma unroll
    for (int j = 0; j < 2; ++j) {
      int idx = tid + j * 256;
      int row = idx >> 2, c8 = (idx & 3) * 8;
      gload16(W + (size_t)(n0 + row) * D_N + k0 + c8, Bs + idx * 8);
    }
    __syncthreads();
    bf8 af[4], bw[2];
#pragma unroll
    for (int mi = 0; mi < 4; ++mi) af[mi] = *(const bf8*)(As + (mi * 16 + c) * 32 + g * 8);
#pragma unroll
    for (int ni = 0; ni < 2; ++ni) bw[ni] = *(const bf8*)(Bs + (wn * 32 + ni * 16 + c) * 32 + g * 8);
#pragma unroll
    for (int mi = 0; mi < 4; ++mi)
#pragma unroll
      for (int ni = 0; ni < 2; ++ni)
        acc[mi][ni] = __builtin_amdgcn_mfma_f32_16x16x32_bf16(af[mi], bw[ni], acc[mi][ni], 0, 0, 0);
    __syncthreads();
  }

#pragma unroll
  for (int mi = 0; mi < 4; ++mi)
#pragma unroll
    for (int ni = 0; ni < 2; ++ni) {
      int ncol = n0 + wn * 32 + ni * 16 + c;
      float bv = bias[ncol];
#pragma unroll
      for (int r = 0; r < 4; ++r) {
        int m = m0 + mi * 16 + g * 4 + r;
        out[(size_t)m * D_N + ncol] = acc[mi][ni][r] + bv;
      }
    }
}

// ---------------- flash attention: L2-direct, static softmax, fp16 bias -------------
// grid 512 x 256thr (4 warps x 32 q). K, V, bias all prefetched one tile ahead.
// launch_bounds(256,1): empirical cap = 256/arg2; the dbuf working set is ~168 VGPR,
// (256,2)'s 128-cap caused scratch spill (R15: WRITE 8.2->11.8MB). Wave count is
// 2048 = 2/SIMD regardless, so VGPR up to 256 costs nothing.
__global__ __launch_bounds__(256, 1) void attn_kernel(const ushort* __restrict__ QF, const ushort* __restrict__ KF,
                                                      const ushort* __restrict__ VF, const ushort* __restrict__ BF,
                                                      ushort* __restrict__ AO) {
  const int tid = threadIdx.x, lane = tid & 63, w = tid >> 6;
  const int l31 = lane & 31, hi = lane >> 5;
  const int raw = blockIdx.x;
  const int bh = (raw & 7) * 4 + ((raw >> 3) & 3);  // 4 heads per XCD
  const int x  = raw >> 5;                           // q-block 0..15
  const int b = bh >> 4, h = bh & 15;
  const int qtile = x * 4 + w;                       // q>>5

  // Q fragments (coalesced fragment-major)
  const ushort* Qp = QF + ((size_t)(bh * 64 + qtile) * 4) * 512 + lane * 8;
  bf8 aq[4];
#pragma unroll
  for (int ks = 0; ks < 4; ++ks) aq[ks] = *(const bf8*)(Qp + ks * 512);

  // uniform bases + fixed per-lane offsets (per-tile advance is uniform arithmetic)
  const ushort* Ku = KF + (size_t)bh * 32 * 8 * 512;
  const ushort* Vu = VF + (size_t)bh * 32 * 8 * 512;
  const ushort* Bu = BF + (size_t)(b * 64 + qtile) * 32 * 2048;
  const int koff = lane * 8;     // elements
  const int boff = lane * 16;    // fp16 elements

  float lr = 0.f;
  f32x16 o0, o1;
#pragma unroll
  for (int r = 0; r < 16; ++r) { o0[r] = 0.f; o1[r] = 0.f; }

  const int CROW0[16] = {0,1,2,3, 8,9,10,11, 16,17,18,19, 24,25,26,27};

  auto LOADK = [&](bf8 (&kf)[4][2], int t) {
    const ushort* p = Ku + (size_t)t * 4096 + koff;
#pragma unroll
    for (int ks = 0; ks < 4; ++ks) {
      kf[ks][0] = *(const bf8*)(p + (ks * 2 + 0) * 512);
      kf[ks][1] = *(const bf8*)(p + (ks * 2 + 1) * 512);
    }
  };
  auto LOADV = [&](bf8 (&vf)[4][2], int t) {
    const ushort* p = Vu + (size_t)t * 4096 + koff;
#pragma unroll
    for (int ks = 0; ks < 4; ++ks) {
      vf[ks][0] = *(const bf8*)(p + (ks * 2 + 0) * 512);
      vf[ks][1] = *(const bf8*)(p + (ks * 2 + 1) * 512);
    }
  };
  auto LOADB = [&](us8 (&bb)[4], int t) {       // 4 x 16B fp16 loads
    const ushort* p = Bu + (size_t)t * 2048 + boff;
    bb[0] = *(const us8*)(p);
    bb[1] = *(const us8*)(p + 8);
    bb[2] = *(const us8*)(p + 1024);
    bb[3] = *(const us8*)(p + 1024 + 8);
  };

  auto TILE = [&](const bf8 (&kf)[4][2], const bf8 (&vf)[4][2], const us8 (&bb)[4]) {
    // scores init = bias (fp16 -> f32 cvt straight into the accumulator)
    f32x16 s0, s1;
#pragma unroll
    for (int g = 0; g < 4; ++g)
#pragma unroll
      for (int j = 0; j < 4; ++j) {
        s0[g * 4 + j] = h2f(bb[g >> 1][(g & 1) * 4 + j]);
        s1[g * 4 + j] = h2f(bb[2 + (g >> 1)][(g & 1) * 4 + j]);
      }
    __builtin_amdgcn_s_setprio(1);
#pragma unroll
    for (int ks = 0; ks < 4; ++ks) {
      s0 = __builtin_amdgcn_mfma_f32_32x32x16_bf16(kf[ks][0], aq[ks], s0, 0, 0, 0);
      s1 = __builtin_amdgcn_mfma_f32_32x32x16_bf16(kf[ks][1], aq[ks], s1, 0, 0, 0);
    }
    __builtin_amdgcn_s_setprio(0);

    // softmax numerator: P = exp2(s) directly; sum lane-locally
#pragma unroll
    for (int r = 0; r < 16; ++r) {
      s0[r] = __builtin_exp2f(s0[r]);
      s1[r] = __builtin_exp2f(s1[r]);
    }
    float a8[8];
#pragma unroll
    for (int r = 0; r < 8; ++r)
      a8[r] = (s0[r] + s0[r + 8]) + (s1[r] + s1[r + 8]);
    lr += ((a8[0] + a8[4]) + (a8[1] + a8[5])) + ((a8[2] + a8[6]) + (a8[3] + a8[7]));

    // P (f32, S^T layout) -> PV A-fragments via cvt_pk + partner exchange
    bf8 pa[4];
#pragma unroll
    for (int t = 0; t < 2; ++t) {
      uint32_t wv[4][2];
#pragma unroll
      for (int g = 0; g < 4; ++g) {
        const float* sp = (t == 0) ? (const float*)&s0 : (const float*)&s1;
        wv[g][0] = cvtpk(sp[g * 4 + 0], sp[g * 4 + 1]);
        wv[g][1] = cvtpk(sp[g * 4 + 2], sp[g * 4 + 3]);
      }
#pragma unroll
      for (int pr = 0; pr < 2; ++pr) {
        uint32_t x0 = hi ? wv[2 * pr][0] : wv[2 * pr + 1][0];
        uint32_t x1 = hi ? wv[2 * pr][1] : wv[2 * pr + 1][1];
        uint32_t r0 = (uint32_t)__shfl_xor((int)x0, 32);
        uint32_t r1 = (uint32_t)__shfl_xor((int)x1, 32);
        uint4 pw;
        pw.x = hi ? r0 : wv[2 * pr][0];
        pw.y = hi ? r1 : wv[2 * pr][1];
        pw.z = hi ? wv[2 * pr + 1][0] : r0;
        pw.w = hi ? wv[2 * pr + 1][1] : r1;
        pa[t * 2 + pr] = __builtin_bit_cast(bf8, pw);
      }
    }

    __builtin_amdgcn_s_setprio(1);
#pragma unroll
    for (int ks = 0; ks < 4; ++ks) {
      o0 = __builtin_amdgcn_mfma_f32_32x32x16_bf16(pa[ks], vf[ks][0], o0, 0, 0, 0);
      o1 = __builtin_amdgcn_mfma_f32_32x32x16_bf16(pa[ks], vf[ks][1], o1, 0, 0, 0);
    }
    __builtin_amdgcn_s_setprio(0);
  };

  bf8 kA[4][2], kB[4][2], vA[4][2], vB[4][2];
  us8 bA[4], bB[4];
  LOADK(kA, 0); LOADB(bA, 0); LOADV(vA, 0);

#pragma unroll 1
  for (int p = 0; p < 15; ++p) {          // tiles 0..29 (steady)
    int t = 2 * p;
    LOADK(kB, t + 1); LOADB(bB, t + 1); LOADV(vB, t + 1);
    TILE(kA, vA, bA);
    LOADK(kA, t + 2); LOADB(bA, t + 2); LOADV(vA, t + 2);
    TILE(kB, vB, bB);
  }
  // tiles 30, 31 (kA/vA/bA hold tile 30 from the last loop iteration)
  LOADK(kB, 31); LOADB(bB, 31); LOADV(vB, 31);
  TILE(kA, vA, bA);
  TILE(kB, vB, bB);

  // combine the two kv halves of l once, then normalize
  lr += __shfl_xor(lr, 32);
  float inv = 1.0f / lr;
#pragma unroll
  for (int r = 0; r < 16; ++r) {
    float ivr = __shfl(inv, CROW0[r] + 4 * hi);
    int q = qtile * 32 + CROW0[r] + 4 * hi;
    size_t base = ((size_t)b * S_N + q) * D_N + h * 64 + l31;
    AO[base]      = f2b(o0[r] * ivr);
    AO[base + 32] = f2b(o1[r] * ivr);
  }
}

extern "C" void kernel_launch(void* const* d_in, const int* in_sizes, int n_in,
                              void* d_out, int out_size, void* d_ws, size_t ws_size,
                              hipStream_t stream) {
  (void)in_sizes; (void)n_in; (void)out_size; (void)ws_size;
  const float* query = (const float*)d_in[0];
  const float* key_  = (const float*)d_in[1];
  const float* value = (const float*)d_in[2];
  const int* fid  = (const int*)d_in[3];
  const int* eid  = (const int*)d_in[4];
  const int* tmid = (const int*)d_in[5];
  const int* ttid = (const int*)d_in[6];
  const int* edid = (const int*)d_in[7];
  const int* rlid = (const int*)d_in[8];
  const float* Wq = (const float*)d_in[9];  const float* bq = (const float*)d_in[10];
  const float* Wk = (const float*)d_in[11]; const float* bk = (const float*)d_in[12];
  const float* Wv = (const float*)d_in[13]; const float* bv = (const float*)d_in[14];
  const float* Wo = (const float*)d_in[15]; const float* bo = (const float*)d_in[16];

  char* ws = (char*)d_ws;
  const size_t MB = 1024 * 1024;
  // Projection phase: Xq 0-8, Xk 8-16, Xv 16-24, Wqb 24-26, Wkb 26-28, Wvb 28-30 (MB).
  // After gemm_qkv those are dead; BF fp16 (16.8MB) overwrites [0,17).
  ushort* Xq  = (ushort*)(ws);
  ushort* Xk  = (ushort*)(ws + 8 * MB);
  ushort* Xv  = (ushort*)(ws + 16 * MB);
  ushort* Wqb = (ushort*)(ws + 24 * MB);
  ushort* Wkb = (ushort*)(ws + 26 * MB);
  ushort* Wvb = (ushort*)(ws + 28 * MB);
  ushort* BF  = (ushort*)(ws);                      // fragment-major fp16 bias
  ushort* QFw = (ushort*)(ws + 30 * MB);
  ushort* KFw = (ushort*)(ws + 38 * MB);
  ushort* VFw = (ushort*)(ws + 46 * MB);
  ushort* AOw = (ushort*)(ws + 54 * MB);
  ushort* Wob = (ushort*)(ws + 62 * MB);
  uint32_t* codes = (uint32_t*)(ws + 64 * MB);
  // total ws use: 64MB + 16KB

  prep_kernel<<<16400, 256, 0, stream>>>(query, key_, value, Wq, Wk, Wv, Wo,
                                         Xq, Xk, Xv, Wqb, Wkb, Wvb, Wob,
                                         fid, eid, tmid, ttid, edid, rlid, codes);
  gemm_qkv<<<dim3(D_N / 128, (B_N * S_N) / 128, 3), 256, 0, stream>>>(
      Xq, Xk, Xv, Wqb, Wkb, Wvb, bq, bk, bv, QFw, KFw, VFw);
  // bias matrix overwrites Xq/Xk/start-of-Xv region (dead after gemm_qkv)
  bias_build<<<4096, 256, 0, stream>>>(codes, BF);
  attn_kernel<<<512, 256, 0, stream>>>(QFw, KFw, VFw, BF, AOw);
  gemm_o<<<dim3(D_N / 128, (B_N * S_N) / 64), 256, 0, stream>>>(AOw, Wob, bo, (float*)d_out);
}

// Round 17
// 154.521 us; speedup vs baseline: 1.1152x; 1.1152x over previous
//
#include <hip/hip_runtime.h>
#include <hip/hip_bf16.h>
#include <stdint.h>

#define B_N 2
#define S_N 2048
#define D_N 1024
#define H_N 16
#define LOG2E 1.44269504f

using bf8    = __attribute__((ext_vector_type(8))) short;   // 8 bf16 (4 VGPRs)
using us8    = __attribute__((ext_vector_type(8))) unsigned short;
using f32x4  = __attribute__((ext_vector_type(4))) float;
using f32x16 = __attribute__((ext_vector_type(16))) float;

static __device__ __forceinline__ ushort f2b(float f) {
  uint32_t u = __builtin_bit_cast(uint32_t, f);
  u += 0x7fffu + ((u >> 16) & 1u);     // RNE
  return (ushort)(u >> 16);
}

static __device__ __forceinline__ uint32_t cvtpk(float a, float b) {
  uint32_t r;
  asm("v_cvt_pk_bf16_f32 %0, %1, %2" : "=v"(r) : "v"(a), "v"(b));
  return r;   // low = a, high = b
}

static __device__ __forceinline__ float h2f(ushort u) {
  return (float)__builtin_bit_cast(_Float16, u);
}

static __device__ __forceinline__ ushort h16(float x) {
  return __builtin_bit_cast(ushort, (_Float16)x);
}

typedef __attribute__((address_space(1))) const uint32_t GU32;
typedef __attribute__((address_space(3))) uint32_t LU32;
static __device__ __forceinline__ void gload16(const void* g, void* l) {
  __builtin_amdgcn_global_load_lds((GU32*)g, (LU32*)l, 16, 0, 0);
}

static __device__ __forceinline__ void cvt4B(const float* __restrict__ s, ushort* __restrict__ d, int i) {
  float4 v = *(const float4*)(s + i);
  ushort4 o;
  o.x = f2b(v.x); o.y = f2b(v.y); o.z = f2b(v.z); o.w = f2b(v.w);
  *(ushort4*)(d + i) = o;
}

// ---------------- fused prep: f32->bf16 converts + code packing ----------------
__global__ __launch_bounds__(256) void prep_kernel(
    const float* __restrict__ q, const float* __restrict__ k, const float* __restrict__ v,
    const float* __restrict__ wq, const float* __restrict__ wk, const float* __restrict__ wv,
    const float* __restrict__ wo,
    ushort* __restrict__ oq, ushort* __restrict__ ok, ushort* __restrict__ ov,
    ushort* __restrict__ owq, ushort* __restrict__ owk, ushort* __restrict__ owv,
    ushort* __restrict__ owo,
    const int* __restrict__ f, const int* __restrict__ e, const int* __restrict__ ti,
    const int* __restrict__ tt, const int* __restrict__ ed, const int* __restrict__ ro,
    uint32_t* __restrict__ codes) {
  int x = blockIdx.x;
  if (x < 12288) {
    int which = x >> 12, i = (x & 4095) * 1024 + threadIdx.x * 4;
    const float* s = (which == 0) ? q : (which == 1) ? k : v;
    ushort* d = (which == 0) ? oq : (which == 1) ? ok : ov;
    cvt4B(s, d, i);
  } else if (x < 16384) {
    int which = (x - 12288) >> 10, i = (x & 1023) * 1024 + threadIdx.x * 4;
    const float* s = (which == 0) ? wq : (which == 1) ? wk : (which == 2) ? wv : wo;
    ushort* d = (which == 0) ? owq : (which == 1) ? owk : (which == 2) ? owv : owo;
    cvt4B(s, d, i);
  } else {
    int i = (x - 16384) * 256 + threadIdx.x;
    uint32_t c = ((uint32_t)f[i] & 31u) | (((uint32_t)e[i] & 63u) << 5) |
                 (((uint32_t)ti[i] & 127u) << 11) | (((uint32_t)tt[i] & 7u) << 18) |
                 (((uint32_t)ro[i] & 7u) << 21) |
                 ((ed[i] != 0) ? (1u << 24) : 0u) | ((f[i] == 0) ? (1u << 25) : 0u);
    codes[i] = c;
  }
}

static __device__ __forceinline__ float bias_val(uint32_t a, uint32_t b) {
  uint32_t x = a ^ b;
  uint32_t o = a | b;
  float v = (o & 0x1000000u) ? 1.5f : 0.0f;   // has_edge
  v += (x & 0x1Fu)     ? 0.0f : 1.0f;          // field
  v += (x & 0x7E0u)    ? 0.0f : 1.0f;          // entity
  v += (x & 0x3F800u)  ? 0.0f : 0.5f;          // time
  v += (x & 0x1C0000u) ? 0.0f : 0.3f;          // token_type
  v += (x & 0xE00000u) ? 0.0f : 0.5f;          // role
  return (o & 0x2000000u) ? -30000.f : v;      // pad -> big negative
}

// Fragment-major fp16 bias, log2e-scaled (no shift needed: softmax cancels constants).
__global__ __launch_bounds__(256) void bias_build(const uint32_t* __restrict__ codes,
                                                  ushort* __restrict__ BF) {
  int t = blockIdx.x * 256 + threadIdx.x;      // 0 .. 2^20-1
  int v8    = t & 1;
  int lane  = (t >> 1) & 63;
  int h     = (t >> 7) & 1;
  int kvt   = (t >> 8) & 31;
  int qtile = (t >> 13) & 63;
  int b     = t >> 19;
  int hi = lane >> 5;
  int q  = qtile * 32 + (lane & 31);
  uint32_t cq = codes[b * S_N + q];
  int kvb = kvt * 64 + h * 32 + v8 * 16 + hi * 4;
  uint4 c0 = *(const uint4*)(codes + b * S_N + kvb);
  uint4 c1 = *(const uint4*)(codes + b * S_N + kvb + 8);
  ushort o[8];
  o[0] = h16(bias_val(cq, c0.x) * LOG2E);
  o[1] = h16(bias_val(cq, c0.y) * LOG2E);
  o[2] = h16(bias_val(cq, c0.z) * LOG2E);
  o[3] = h16(bias_val(cq, c0.w) * LOG2E);
  o[4] = h16(bias_val(cq, c1.x) * LOG2E);
  o[5] = h16(bias_val(cq, c1.y) * LOG2E);
  o[6] = h16(bias_val(cq, c1.z) * LOG2E);
  o[7] = h16(bias_val(cq, c1.w) * LOG2E);
  *(uint4*)(BF + (size_t)t * 8) = *(const uint4*)o;
}

// ---------------- GEMM core: C[M,N] = A[M,K] @ W[N,K]^T + bias ----------------
// MODE 0: Q fragment-major; MODE 3: K fragment-major; MODE 2: V fragment-major.
template <int MODE>
static __device__ __forceinline__ void gemm_core(ushort* As, ushort* Bs,
    const ushort* __restrict__ A, const ushort* __restrict__ W, const float* __restrict__ bias,
    void* __restrict__ out, float scale) {
  const int tid = threadIdx.x, lane = tid & 63, wid = tid >> 6;
  const int g = lane >> 4, c = lane & 15;
  const int wm = wid >> 1, wn = wid & 1;
  const int m0 = blockIdx.y * 128, n0 = blockIdx.x * 128;

  f32x4 acc[4][4];
#pragma unroll
  for (int i = 0; i < 4; ++i)
#pragma unroll
    for (int j = 0; j < 4; ++j) acc[i][j] = (f32x4){0.f, 0.f, 0.f, 0.f};

  for (int k0 = 0; k0 < D_N; k0 += 32) {
#pragma unroll
    for (int j = 0; j < 2; ++j) {
      int idx = tid + j * 256;                  // 0..511
      int row = idx >> 2, c8 = (idx & 3) * 8;
      gload16(A + (size_t)(m0 + row) * D_N + k0 + c8, As + idx * 8);
      gload16(W + (size_t)(n0 + row) * D_N + k0 + c8, Bs + idx * 8);
    }
    __syncthreads();
    bf8 af[4], bw[4];
#pragma unroll
    for (int mi = 0; mi < 4; ++mi) af[mi] = *(const bf8*)(As + (wm * 64 + mi * 16 + c) * 32 + g * 8);
#pragma unroll
    for (int ni = 0; ni < 4; ++ni) bw[ni] = *(const bf8*)(Bs + (wn * 64 + ni * 16 + c) * 32 + g * 8);
#pragma unroll
    for (int mi = 0; mi < 4; ++mi)
#pragma unroll
      for (int ni = 0; ni < 4; ++ni)
        acc[mi][ni] = __builtin_amdgcn_mfma_f32_16x16x32_bf16(af[mi], bw[ni], acc[mi][ni], 0, 0, 0);
    __syncthreads();
  }

#pragma unroll
  for (int mi = 0; mi < 4; ++mi)
#pragma unroll
    for (int ni = 0; ni < 4; ++ni) {
      int ncol = n0 + wn * 64 + ni * 16 + c;
      float bv = bias[ncol];
      int hh = ncol >> 6, dd = ncol & 63;
      if (MODE == 2) {
        int mb = m0 + wm * 64 + mi * 16 + g * 4;
        int bb = mb >> 11, kv = mb & 2047;
        int kvt = kv >> 6, kin = kv & 63;
        int ks = kin >> 4, hif = (kin >> 3) & 1, e = kin & 7;
        int jj = dd >> 5, l31v = dd & 31;
        int lanef = hif * 32 + l31v;
        size_t off = (((size_t)(bb * H_N + hh) * 32 + kvt) * 8 + ks * 2 + jj) * 512 + lanef * 8 + e;
        ushort4 o4;
        o4.x = f2b((acc[mi][ni][0] + bv) * scale);
        o4.y = f2b((acc[mi][ni][1] + bv) * scale);
        o4.z = f2b((acc[mi][ni][2] + bv) * scale);
        o4.w = f2b((acc[mi][ni][3] + bv) * scale);
        *(ushort4*)((ushort*)out + off) = o4;
      } else {
#pragma unroll
        for (int r = 0; r < 4; ++r) {
          int m = m0 + wm * 64 + mi * 16 + g * 4 + r;
          float v = (acc[mi][ni][r] + bv) * scale;
          if (MODE == 0) {
            int bb = m >> 11, q = m & 2047;
            int qtile = q >> 5, l31q = q & 31;
            int ks = dd >> 4, hif = (dd >> 3) & 1, e = dd & 7;
            int lanef = hif * 32 + l31q;
            size_t off = (((size_t)(bb * H_N + hh) * 64 + qtile) * 4 + ks) * 512 + lanef * 8 + e;
            ((ushort*)out)[off] = f2b(v);
          } else {
            int bb = m >> 11, s = m & 2047;
            int kvt = s >> 6, sin = s & 63;
            int jj = sin >> 5, l31k = sin & 31;
            int ks = dd >> 4, hif = (dd >> 3) & 1, e = dd & 7;
            int lanef = hif * 32 + l31k;
            size_t off = (((size_t)(bb * H_N + hh) * 32 + kvt) * 8 + ks * 2 + jj) * 512 + lanef * 8 + e;
            ((ushort*)out)[off] = f2b(v);
          }
        }
      }
    }
}

__global__ __launch_bounds__(256) void gemm_qkv(
    const ushort* __restrict__ Xq, const ushort* __restrict__ Xk, const ushort* __restrict__ Xv,
    const ushort* __restrict__ Wq, const ushort* __restrict__ Wk, const ushort* __restrict__ Wv,
    const float* __restrict__ bq, const float* __restrict__ bk, const float* __restrict__ bv,
    ushort* __restrict__ Qo, ushort* __restrict__ Ko, ushort* __restrict__ Vo) {
  __shared__ __align__(16) ushort As[128 * 32];
  __shared__ __align__(16) ushort Bs[128 * 32];
  // Q carries 1/sqrt(64) * log2(e) so softmax runs in exp2 domain
  if (blockIdx.z == 0)      gemm_core<0>(As, Bs, Xq, Wq, bq, Qo, 0.125f * LOG2E);
  else if (blockIdx.z == 1) gemm_core<3>(As, Bs, Xk, Wk, bk, Ko, 1.0f);
  else                      gemm_core<2>(As, Bs, Xv, Wv, bv, Vo, 1.0f);
}

// gemm_o: 64x128 tiles -> grid (8, 64) = 512 blocks = 2 blocks/CU.
__global__ __launch_bounds__(256) void gemm_o(const ushort* __restrict__ A, const ushort* __restrict__ W,
                                              const float* __restrict__ bias, float* __restrict__ out) {
  __shared__ __align__(16) ushort As[64 * 32];
  __shared__ __align__(16) ushort Bs[128 * 32];
  const int tid = threadIdx.x, lane = tid & 63, wn = tid >> 6;
  const int g = lane >> 4, c = lane & 15;
  const int m0 = blockIdx.y * 64, n0 = blockIdx.x * 128;

  f32x4 acc[4][2];
#pragma unroll
  for (int i = 0; i < 4; ++i)
#pragma unroll
    for (int j = 0; j < 2; ++j) acc[i][j] = (f32x4){0.f, 0.f, 0.f, 0.f};

  for (int k0 = 0; k0 < D_N; k0 += 32) {
    {
      int row = tid >> 2, c8 = (tid & 3) * 8;
      gload16(A + (size_t)(m0 + row) * D_N + k0 + c8, As + tid * 8);
    }
#pragma unroll
    for (int j = 0; j < 2; ++j) {
      int idx = tid + j * 256;
      int row = idx >> 2, c8 = (idx & 3) * 8;
      gload16(W + (size_t)(n0 + row) * D_N + k0 + c8, Bs + idx * 8);
    }
    __syncthreads();
    bf8 af[4], bw[2];
#pragma unroll
    for (int mi = 0; mi < 4; ++mi) af[mi] = *(const bf8*)(As + (mi * 16 + c) * 32 + g * 8);
#pragma unroll
    for (int ni = 0; ni < 2; ++ni) bw[ni] = *(const bf8*)(Bs + (wn * 32 + ni * 16 + c) * 32 + g * 8);
#pragma unroll
    for (int mi = 0; mi < 4; ++mi)
#pragma unroll
      for (int ni = 0; ni < 2; ++ni)
        acc[mi][ni] = __builtin_amdgcn_mfma_f32_16x16x32_bf16(af[mi], bw[ni], acc[mi][ni], 0, 0, 0);
    __syncthreads();
  }

#pragma unroll
  for (int mi = 0; mi < 4; ++mi)
#pragma unroll
    for (int ni = 0; ni < 2; ++ni) {
      int ncol = n0 + wn * 32 + ni * 16 + c;
      float bv = bias[ncol];
#pragma unroll
      for (int r = 0; r < 4; ++r) {
        int m = m0 + mi * 16 + g * 4 + r;
        out[(size_t)m * D_N + ncol] = acc[mi][ni][r] + bv;
      }
    }
}

// ---------------- flash attention: L2-direct, static softmax, fp16 bias -------------
// grid 512 x 256thr (4 warps x 32 q). Exact R11 configuration (proven 80.7us):
// (256,2), K + bias one tile ahead, V issued at tile start (same-tile).
// V-prefetch experiments: cap128 -> spill (R15), cap256 -> VGPR164/occupancy loss (R16).
__global__ __launch_bounds__(256, 2) void attn_kernel(const ushort* __restrict__ QF, const ushort* __restrict__ KF,
                                                      const ushort* __restrict__ VF, const ushort* __restrict__ BF,
                                                      ushort* __restrict__ AO) {
  const int tid = threadIdx.x, lane = tid & 63, w = tid >> 6;
  const int l31 = lane & 31, hi = lane >> 5;
  const int raw = blockIdx.x;
  const int bh = (raw & 7) * 4 + ((raw >> 3) & 3);  // 4 heads per XCD
  const int x  = raw >> 5;                           // q-block 0..15
  const int b = bh >> 4, h = bh & 15;
  const int qtile = x * 4 + w;                       // q>>5

  // Q fragments (coalesced fragment-major)
  const ushort* Qp = QF + ((size_t)(bh * 64 + qtile) * 4) * 512 + lane * 8;
  bf8 aq[4];
#pragma unroll
  for (int ks = 0; ks < 4; ++ks) aq[ks] = *(const bf8*)(Qp + ks * 512);

  // uniform bases + fixed per-lane offsets (per-tile advance is uniform arithmetic)
  const ushort* Ku = KF + (size_t)bh * 32 * 8 * 512;
  const ushort* Vu = VF + (size_t)bh * 32 * 8 * 512;
  const ushort* Bu = BF + (size_t)(b * 64 + qtile) * 32 * 2048;
  const int koff = lane * 8;     // elements
  const int boff = lane * 16;    // fp16 elements

  float lr = 0.f;
  f32x16 o0, o1;
#pragma unroll
  for (int r = 0; r < 16; ++r) { o0[r] = 0.f; o1[r] = 0.f; }

  const int CROW0[16] = {0,1,2,3, 8,9,10,11, 16,17,18,19, 24,25,26,27};

  auto LOADK = [&](bf8 (&kf)[4][2], int t) {
    const ushort* p = Ku + (size_t)t * 4096 + koff;
#pragma unroll
    for (int ks = 0; ks < 4; ++ks) {
      kf[ks][0] = *(const bf8*)(p + (ks * 2 + 0) * 512);
      kf[ks][1] = *(const bf8*)(p + (ks * 2 + 1) * 512);
    }
  };
  auto LOADV = [&](bf8 (&vf)[4][2], int t) {
    const ushort* p = Vu + (size_t)t * 4096 + koff;
#pragma unroll
    for (int ks = 0; ks < 4; ++ks) {
      vf[ks][0] = *(const bf8*)(p + (ks * 2 + 0) * 512);
      vf[ks][1] = *(const bf8*)(p + (ks * 2 + 1) * 512);
    }
  };
  auto LOADB = [&](us8 (&bb)[4], int t) {       // 4 x 16B fp16 loads
    const ushort* p = Bu + (size_t)t * 2048 + boff;
    bb[0] = *(const us8*)(p);
    bb[1] = *(const us8*)(p + 8);
    bb[2] = *(const us8*)(p + 1024);
    bb[3] = *(const us8*)(p + 1024 + 8);
  };

  auto TILE = [&](const bf8 (&kf)[4][2], const bf8 (&vf)[4][2], const us8 (&bb)[4]) {
    // scores init = bias (fp16 -> f32 cvt straight into the accumulator)
    f32x16 s0, s1;
#pragma unroll
    for (int g = 0; g < 4; ++g)
#pragma unroll
      for (int j = 0; j < 4; ++j) {
        s0[g * 4 + j] = h2f(bb[g >> 1][(g & 1) * 4 + j]);
        s1[g * 4 + j] = h2f(bb[2 + (g >> 1)][(g & 1) * 4 + j]);
      }
    __builtin_amdgcn_s_setprio(1);
#pragma unroll
    for (int ks = 0; ks < 4; ++ks) {
      s0 = __builtin_amdgcn_mfma_f32_32x32x16_bf16(kf[ks][0], aq[ks], s0, 0, 0, 0);
      s1 = __builtin_amdgcn_mfma_f32_32x32x16_bf16(kf[ks][1], aq[ks], s1, 0, 0, 0);
    }
    __builtin_amdgcn_s_setprio(0);

    // softmax numerator: P = exp2(s) directly; sum lane-locally
#pragma unroll
    for (int r = 0; r < 16; ++r) {
      s0[r] = __builtin_exp2f(s0[r]);
      s1[r] = __builtin_exp2f(s1[r]);
    }
    float a8[8];
#pragma unroll
    for (int r = 0; r < 8; ++r)
      a8[r] = (s0[r] + s0[r + 8]) + (s1[r] + s1[r + 8]);
    lr += ((a8[0] + a8[4]) + (a8[1] + a8[5])) + ((a8[2] + a8[6]) + (a8[3] + a8[7]));

    // P (f32, S^T layout) -> PV A-fragments via cvt_pk + partner exchange
    bf8 pa[4];
#pragma unroll
    for (int t = 0; t < 2; ++t) {
      uint32_t wv[4][2];
#pragma unroll
      for (int g = 0; g < 4; ++g) {
        const float* sp = (t == 0) ? (const float*)&s0 : (const float*)&s1;
        wv[g][0] = cvtpk(sp[g * 4 + 0], sp[g * 4 + 1]);
        wv[g][1] = cvtpk(sp[g * 4 + 2], sp[g * 4 + 3]);
      }
#pragma unroll
      for (int pr = 0; pr < 2; ++pr) {
        uint32_t x0 = hi ? wv[2 * pr][0] : wv[2 * pr + 1][0];
        uint32_t x1 = hi ? wv[2 * pr][1] : wv[2 * pr + 1][1];
        uint32_t r0 = (uint32_t)__shfl_xor((int)x0, 32);
        uint32_t r1 = (uint32_t)__shfl_xor((int)x1, 32);
        uint4 pw;
        pw.x = hi ? r0 : wv[2 * pr][0];
        pw.y = hi ? r1 : wv[2 * pr][1];
        pw.z = hi ? wv[2 * pr + 1][0] : r0;
        pw.w = hi ? wv[2 * pr + 1][1] : r1;
        pa[t * 2 + pr] = __builtin_bit_cast(bf8, pw);
      }
    }

    __builtin_amdgcn_s_setprio(1);
#pragma unroll
    for (int ks = 0; ks < 4; ++ks) {
      o0 = __builtin_amdgcn_mfma_f32_32x32x16_bf16(pa[ks], vf[ks][0], o0, 0, 0, 0);
      o1 = __builtin_amdgcn_mfma_f32_32x32x16_bf16(pa[ks], vf[ks][1], o1, 0, 0, 0);
    }
    __builtin_amdgcn_s_setprio(0);
  };

  bf8 kA[4][2], kB[4][2], vC[4][2];
  us8 bA[4], bB[4];
  LOADK(kA, 0); LOADB(bA, 0);

#pragma unroll 1
  for (int p = 0; p < 15; ++p) {          // tiles 0..29 (steady)
    int t = 2 * p;
    LOADK(kB, t + 1); LOADB(bB, t + 1); LOADV(vC, t);
    TILE(kA, vC, bA);
    LOADK(kA, t + 2); LOADB(bA, t + 2); LOADV(vC, t + 1);
    TILE(kB, vC, bB);
  }
  // tiles 30, 31
  LOADK(kB, 31); LOADB(bB, 31); LOADV(vC, 30);
  TILE(kA, vC, bA);
  LOADV(vC, 31);
  TILE(kB, vC, bB);

  // combine the two kv halves of l once, then normalize
  lr += __shfl_xor(lr, 32);
  float inv = 1.0f / lr;
#pragma unroll
  for (int r = 0; r < 16; ++r) {
    float ivr = __shfl(inv, CROW0[r] + 4 * hi);
    int q = qtile * 32 + CROW0[r] + 4 * hi;
    size_t base = ((size_t)b * S_N + q) * D_N + h * 64 + l31;
    AO[base]      = f2b(o0[r] * ivr);
    AO[base + 32] = f2b(o1[r] * ivr);
  }
}

extern "C" void kernel_launch(void* const* d_in, const int* in_sizes, int n_in,
                              void* d_out, int out_size, void* d_ws, size_t ws_size,
                              hipStream_t stream) {
  (void)in_sizes; (void)n_in; (void)out_size; (void)ws_size;
  const float* query = (const float*)d_in[0];
  const float* key_  = (const float*)d_in[1];
  const float* value = (const float*)d_in[2];
  const int* fid  = (const int*)d_in[3];
  const int* eid  = (const int*)d_in[4];
  const int* tmid = (const int*)d_in[5];
  const int* ttid = (const int*)d_in[6];
  const int* edid = (const int*)d_in[7];
  const int* rlid = (const int*)d_in[8];
  const float* Wq = (const float*)d_in[9];  const float* bq = (const float*)d_in[10];
  const float* Wk = (const float*)d_in[11]; const float* bk = (const float*)d_in[12];
  const float* Wv = (const float*)d_in[13]; const float* bv = (const float*)d_in[14];
  const float* Wo = (const float*)d_in[15]; const float* bo = (const float*)d_in[16];

  char* ws = (char*)d_ws;
  const size_t MB = 1024 * 1024;
  // Projection phase: Xq 0-8, Xk 8-16, Xv 16-24, Wqb 24-26, Wkb 26-28, Wvb 28-30 (MB).
  // After gemm_qkv those are dead; BF fp16 (16.8MB) overwrites [0,17).
  ushort* Xq  = (ushort*)(ws);
  ushort* Xk  = (ushort*)(ws + 8 * MB);
  ushort* Xv  = (ushort*)(ws + 16 * MB);
  ushort* Wqb = (ushort*)(ws + 24 * MB);
  ushort* Wkb = (ushort*)(ws + 26 * MB);
  ushort* Wvb = (ushort*)(ws + 28 * MB);
  ushort* BF  = (ushort*)(ws);                      // fragment-major fp16 bias
  ushort* QFw = (ushort*)(ws + 30 * MB);
  ushort* KFw = (ushort*)(ws + 38 * MB);
  ushort* VFw = (ushort*)(ws + 46 * MB);
  ushort* AOw = (ushort*)(ws + 54 * MB);
  ushort* Wob = (ushort*)(ws + 62 * MB);
  uint32_t* codes = (uint32_t*)(ws + 64 * MB);
  // total ws use: 64MB + 16KB

  prep_kernel<<<16400, 256, 0, stream>>>(query, key_, value, Wq, Wk, Wv, Wo,
                                         Xq, Xk, Xv, Wqb, Wkb, Wvb, Wob,
                                         fid, eid, tmid, ttid, edid, rlid, codes);
  gemm_qkv<<<dim3(D_N / 128, (B_N * S_N) / 128, 3), 256, 0, stream>>>(
      Xq, Xk, Xv, Wqb, Wkb, Wvb, bq, bk, bv, QFw, KFw, VFw);
  // bias matrix overwrites Xq/Xk/start-of-Xv region (dead after gemm_qkv)
  bias_build<<<4096, 256, 0, stream>>>(codes, BF);
  attn_kernel<<<512, 256, 0, stream>>>(QFw, KFw, VFw, BF, AOw);
  gemm_o<<<dim3(D_N / 128, (B_N * S_N) / 64), 256, 0, stream>>>(AOw, Wob, bo, (float*)d_out);
}

// Round 19
// 143.058 us; speedup vs baseline: 1.2045x; 1.0801x over previous
//
#include <hip/hip_runtime.h>
#include <hip/hip_bf16.h>
#include <stdint.h>

#define B_N 2
#define S_N 2048
#define D_N 1024
#define H_N 16
#define LOG2E 1.44269504f

using bf8    = __attribute__((ext_vector_type(8))) short;   // 8 bf16 (4 VGPRs)
using us8    = __attribute__((ext_vector_type(8))) unsigned short;
using f32x4  = __attribute__((ext_vector_type(4))) float;
using f32x16 = __attribute__((ext_vector_type(16))) float;

static __device__ __forceinline__ ushort f2b(float f) {
  uint32_t u = __builtin_bit_cast(uint32_t, f);
  u += 0x7fffu + ((u >> 16) & 1u);     // RNE
  return (ushort)(u >> 16);
}

static __device__ __forceinline__ uint32_t cvtpk(float a, float b) {
  uint32_t r;
  asm("v_cvt_pk_bf16_f32 %0, %1, %2" : "=v"(r) : "v"(a), "v"(b));
  return r;   // low = a, high = b
}

static __device__ __forceinline__ float h2f(ushort u) {
  return (float)__builtin_bit_cast(_Float16, u);
}

static __device__ __forceinline__ ushort h16(float x) {
  return __builtin_bit_cast(ushort, (_Float16)x);
}

// raw v_exp_f32 via the amdgcn builtin: no denormal-fixup wrapper, but the compiler
// knows the instruction (TRANS hazard wait-states handled — R18's bare inline asm
// skipped them and corrupted results).
static __device__ __forceinline__ float exp2raw(float x) {
  return __builtin_amdgcn_exp2f(x);
}

typedef __attribute__((address_space(1))) const uint32_t GU32;
typedef __attribute__((address_space(3))) uint32_t LU32;
static __device__ __forceinline__ void gload16(const void* g, void* l) {
  __builtin_amdgcn_global_load_lds((GU32*)g, (LU32*)l, 16, 0, 0);
}

static __device__ __forceinline__ void cvt4B(const float* __restrict__ s, ushort* __restrict__ d, int i) {
  float4 v = *(const float4*)(s + i);
  ushort4 o;
  o.x = f2b(v.x); o.y = f2b(v.y); o.z = f2b(v.z); o.w = f2b(v.w);
  *(ushort4*)(d + i) = o;
}

// ---------------- fused prep: f32->bf16 converts + code packing ----------------
__global__ __launch_bounds__(256) void prep_kernel(
    const float* __restrict__ q, const float* __restrict__ k, const float* __restrict__ v,
    const float* __restrict__ wq, const float* __restrict__ wk, const float* __restrict__ wv,
    const float* __restrict__ wo,
    ushort* __restrict__ oq, ushort* __restrict__ ok, ushort* __restrict__ ov,
    ushort* __restrict__ owq, ushort* __restrict__ owk, ushort* __restrict__ owv,
    ushort* __restrict__ owo,
    const int* __restrict__ f, const int* __restrict__ e, const int* __restrict__ ti,
    const int* __restrict__ tt, const int* __restrict__ ed, const int* __restrict__ ro,
    uint32_t* __restrict__ codes) {
  int x = blockIdx.x;
  if (x < 12288) {
    int which = x >> 12, i = (x & 4095) * 1024 + threadIdx.x * 4;
    const float* s = (which == 0) ? q : (which == 1) ? k : v;
    ushort* d = (which == 0) ? oq : (which == 1) ? ok : ov;
    cvt4B(s, d, i);
  } else if (x < 16384) {
    int which = (x - 12288) >> 10, i = (x & 1023) * 1024 + threadIdx.x * 4;
    const float* s = (which == 0) ? wq : (which == 1) ? wk : (which == 2) ? wv : wo;
    ushort* d = (which == 0) ? owq : (which == 1) ? owk : (which == 2) ? owv : owo;
    cvt4B(s, d, i);
  } else {
    int i = (x - 16384) * 256 + threadIdx.x;
    uint32_t c = ((uint32_t)f[i] & 31u) | (((uint32_t)e[i] & 63u) << 5) |
                 (((uint32_t)ti[i] & 127u) << 11) | (((uint32_t)tt[i] & 7u) << 18) |
                 (((uint32_t)ro[i] & 7u) << 21) |
                 ((ed[i] != 0) ? (1u << 24) : 0u) | ((f[i] == 0) ? (1u << 25) : 0u);
    codes[i] = c;
  }
}

static __device__ __forceinline__ float bias_val(uint32_t a, uint32_t b) {
  uint32_t x = a ^ b;
  uint32_t o = a | b;
  float v = (o & 0x1000000u) ? 1.5f : 0.0f;   // has_edge
  v += (x & 0x1Fu)     ? 0.0f : 1.0f;          // field
  v += (x & 0x7E0u)    ? 0.0f : 1.0f;          // entity
  v += (x & 0x3F800u)  ? 0.0f : 0.5f;          // time
  v += (x & 0x1C0000u) ? 0.0f : 0.3f;          // token_type
  v += (x & 0xE00000u) ? 0.0f : 0.5f;          // role
  return (o & 0x2000000u) ? -30000.f : v;      // pad -> big negative
}

// Fragment-major fp16 bias, log2e-scaled (no shift needed: softmax cancels constants).
__global__ __launch_bounds__(256) void bias_build(const uint32_t* __restrict__ codes,
                                                  ushort* __restrict__ BF) {
  int t = blockIdx.x * 256 + threadIdx.x;      // 0 .. 2^20-1
  int v8    = t & 1;
  int lane  = (t >> 1) & 63;
  int h     = (t >> 7) & 1;
  int kvt   = (t >> 8) & 31;
  int qtile = (t >> 13) & 63;
  int b     = t >> 19;
  int hi = lane >> 5;
  int q  = qtile * 32 + (lane & 31);
  uint32_t cq = codes[b * S_N + q];
  int kvb = kvt * 64 + h * 32 + v8 * 16 + hi * 4;
  uint4 c0 = *(const uint4*)(codes + b * S_N + kvb);
  uint4 c1 = *(const uint4*)(codes + b * S_N + kvb + 8);
  ushort o[8];
  o[0] = h16(bias_val(cq, c0.x) * LOG2E);
  o[1] = h16(bias_val(cq, c0.y) * LOG2E);
  o[2] = h16(bias_val(cq, c0.z) * LOG2E);
  o[3] = h16(bias_val(cq, c0.w) * LOG2E);
  o[4] = h16(bias_val(cq, c1.x) * LOG2E);
  o[5] = h16(bias_val(cq, c1.y) * LOG2E);
  o[6] = h16(bias_val(cq, c1.z) * LOG2E);
  o[7] = h16(bias_val(cq, c1.w) * LOG2E);
  *(uint4*)(BF + (size_t)t * 8) = *(const uint4*)o;
}

// ---------------- GEMM core: C[M,N] = A[M,K] @ W[N,K]^T + bias ----------------
// MODE 0: Q fragment-major; MODE 3: K fragment-major; MODE 2: V fragment-major.
template <int MODE>
static __device__ __forceinline__ void gemm_core(ushort* As, ushort* Bs,
    const ushort* __restrict__ A, const ushort* __restrict__ W, const float* __restrict__ bias,
    void* __restrict__ out, float scale) {
  const int tid = threadIdx.x, lane = tid & 63, wid = tid >> 6;
  const int g = lane >> 4, c = lane & 15;
  const int wm = wid >> 1, wn = wid & 1;
  const int m0 = blockIdx.y * 128, n0 = blockIdx.x * 128;

  f32x4 acc[4][4];
#pragma unroll
  for (int i = 0; i < 4; ++i)
#pragma unroll
    for (int j = 0; j < 4; ++j) acc[i][j] = (f32x4){0.f, 0.f, 0.f, 0.f};

  for (int k0 = 0; k0 < D_N; k0 += 32) {
#pragma unroll
    for (int j = 0; j < 2; ++j) {
      int idx = tid + j * 256;                  // 0..511
      int row = idx >> 2, c8 = (idx & 3) * 8;
      gload16(A + (size_t)(m0 + row) * D_N + k0 + c8, As + idx * 8);
      gload16(W + (size_t)(n0 + row) * D_N + k0 + c8, Bs + idx * 8);
    }
    __syncthreads();
    bf8 af[4], bw[4];
#pragma unroll
    for (int mi = 0; mi < 4; ++mi) af[mi] = *(const bf8*)(As + (wm * 64 + mi * 16 + c) * 32 + g * 8);
#pragma unroll
    for (int ni = 0; ni < 4; ++ni) bw[ni] = *(const bf8*)(Bs + (wn * 64 + ni * 16 + c) * 32 + g * 8);
#pragma unroll
    for (int mi = 0; mi < 4; ++mi)
#pragma unroll
      for (int ni = 0; ni < 4; ++ni)
        acc[mi][ni] = __builtin_amdgcn_mfma_f32_16x16x32_bf16(af[mi], bw[ni], acc[mi][ni], 0, 0, 0);
    __syncthreads();
  }

#pragma unroll
  for (int mi = 0; mi < 4; ++mi)
#pragma unroll
    for (int ni = 0; ni < 4; ++ni) {
      int ncol = n0 + wn * 64 + ni * 16 + c;
      float bv = bias[ncol];
      int hh = ncol >> 6, dd = ncol & 63;
      if (MODE == 2) {
        int mb = m0 + wm * 64 + mi * 16 + g * 4;
        int bb = mb >> 11, kv = mb & 2047;
        int kvt = kv >> 6, kin = kv & 63;
        int ks = kin >> 4, hif = (kin >> 3) & 1, e = kin & 7;
        int jj = dd >> 5, l31v = dd & 31;
        int lanef = hif * 32 + l31v;
        size_t off = (((size_t)(bb * H_N + hh) * 32 + kvt) * 8 + ks * 2 + jj) * 512 + lanef * 8 + e;
        ushort4 o4;
        o4.x = f2b((acc[mi][ni][0] + bv) * scale);
        o4.y = f2b((acc[mi][ni][1] + bv) * scale);
        o4.z = f2b((acc[mi][ni][2] + bv) * scale);
        o4.w = f2b((acc[mi][ni][3] + bv) * scale);
        *(ushort4*)((ushort*)out + off) = o4;
      } else {
#pragma unroll
        for (int r = 0; r < 4; ++r) {
          int m = m0 + wm * 64 + mi * 16 + g * 4 + r;
          float v = (acc[mi][ni][r] + bv) * scale;
          if (MODE == 0) {
            int bb = m >> 11, q = m & 2047;
            int qtile = q >> 5, l31q = q & 31;
            int ks = dd >> 4, hif = (dd >> 3) & 1, e = dd & 7;
            int lanef = hif * 32 + l31q;
            size_t off = (((size_t)(bb * H_N + hh) * 64 + qtile) * 4 + ks) * 512 + lanef * 8 + e;
            ((ushort*)out)[off] = f2b(v);
          } else {
            int bb = m >> 11, s = m & 2047;
            int kvt = s >> 6, sin = s & 63;
            int jj = sin >> 5, l31k = sin & 31;
            int ks = dd >> 4, hif = (dd >> 3) & 1, e = dd & 7;
            int lanef = hif * 32 + l31k;
            size_t off = (((size_t)(bb * H_N + hh) * 32 + kvt) * 8 + ks * 2 + jj) * 512 + lanef * 8 + e;
            ((ushort*)out)[off] = f2b(v);
          }
        }
      }
    }
}

__global__ __launch_bounds__(256) void gemm_qkv(
    const ushort* __restrict__ Xq, const ushort* __restrict__ Xk, const ushort* __restrict__ Xv,
    const ushort* __restrict__ Wq, const ushort* __restrict__ Wk, const ushort* __restrict__ Wv,
    const float* __restrict__ bq, const float* __restrict__ bk, const float* __restrict__ bv,
    ushort* __restrict__ Qo, ushort* __restrict__ Ko, ushort* __restrict__ Vo) {
  __shared__ __align__(16) ushort As[128 * 32];
  __shared__ __align__(16) ushort Bs[128 * 32];
  // Q carries 1/sqrt(64) * log2(e) so softmax runs in exp2 domain
  if (blockIdx.z == 0)      gemm_core<0>(As, Bs, Xq, Wq, bq, Qo, 0.125f * LOG2E);
  else if (blockIdx.z == 1) gemm_core<3>(As, Bs, Xk, Wk, bk, Ko, 1.0f);
  else                      gemm_core<2>(As, Bs, Xv, Wv, bv, Vo, 1.0f);
}

// gemm_o: 64x128 tiles -> grid (8, 64) = 512 blocks = 2 blocks/CU.
__global__ __launch_bounds__(256) void gemm_o(const ushort* __restrict__ A, const ushort* __restrict__ W,
                                              const float* __restrict__ bias, float* __restrict__ out) {
  __shared__ __align__(16) ushort As[64 * 32];
  __shared__ __align__(16) ushort Bs[128 * 32];
  const int tid = threadIdx.x, lane = tid & 63, wn = tid >> 6;
  const int g = lane >> 4, c = lane & 15;
  const int m0 = blockIdx.y * 64, n0 = blockIdx.x * 128;

  f32x4 acc[4][2];
#pragma unroll
  for (int i = 0; i < 4; ++i)
#pragma unroll
    for (int j = 0; j < 2; ++j) acc[i][j] = (f32x4){0.f, 0.f, 0.f, 0.f};

  for (int k0 = 0; k0 < D_N; k0 += 32) {
    {
      int row = tid >> 2, c8 = (tid & 3) * 8;
      gload16(A + (size_t)(m0 + row) * D_N + k0 + c8, As + tid * 8);
    }
#pragma unroll
    for (int j = 0; j < 2; ++j) {
      int idx = tid + j * 256;
      int row = idx >> 2, c8 = (idx & 3) * 8;
      gload16(W + (size_t)(n0 + row) * D_N + k0 + c8, Bs + idx * 8);
    }
    __syncthreads();
    bf8 af[4], bw[2];
#pragma unroll
    for (int mi = 0; mi < 4; ++mi) af[mi] = *(const bf8*)(As + (mi * 16 + c) * 32 + g * 8);
#pragma unroll
    for (int ni = 0; ni < 2; ++ni) bw[ni] = *(const bf8*)(Bs + (wn * 32 + ni * 16 + c) * 32 + g * 8);
#pragma unroll
    for (int mi = 0; mi < 4; ++mi)
#pragma unroll
      for (int ni = 0; ni < 2; ++ni)
        acc[mi][ni] = __builtin_amdgcn_mfma_f32_16x16x32_bf16(af[mi], bw[ni], acc[mi][ni], 0, 0, 0);
    __syncthreads();
  }

#pragma unroll
  for (int mi = 0; mi < 4; ++mi)
#pragma unroll
    for (int ni = 0; ni < 2; ++ni) {
      int ncol = n0 + wn * 32 + ni * 16 + c;
      float bv = bias[ncol];
#pragma unroll
      for (int r = 0; r < 4; ++r) {
        int m = m0 + mi * 16 + g * 4 + r;
        out[(size_t)m * D_N + ncol] = acc[mi][ni][r] + bv;
      }
    }
}

// ---------------- flash attention: L2-direct, static softmax, fp16 bias -------------
// grid 512 x 256thr (4 warps x 32 q). R17 configuration + __builtin_amdgcn_exp2f.
__global__ __launch_bounds__(256, 2) void attn_kernel(const ushort* __restrict__ QF, const ushort* __restrict__ KF,
                                                      const ushort* __restrict__ VF, const ushort* __restrict__ BF,
                                                      ushort* __restrict__ AO) {
  const int tid = threadIdx.x, lane = tid & 63, w = tid >> 6;
  const int l31 = lane & 31, hi = lane >> 5;
  const int raw = blockIdx.x;
  const int bh = (raw & 7) * 4 + ((raw >> 3) & 3);  // 4 heads per XCD
  const int x  = raw >> 5;                           // q-block 0..15
  const int b = bh >> 4, h = bh & 15;
  const int qtile = x * 4 + w;                       // q>>5

  // Q fragments (coalesced fragment-major)
  const ushort* Qp = QF + ((size_t)(bh * 64 + qtile) * 4) * 512 + lane * 8;
  bf8 aq[4];
#pragma unroll
  for (int ks = 0; ks < 4; ++ks) aq[ks] = *(const bf8*)(Qp + ks * 512);

  // uniform bases + fixed per-lane offsets (per-tile advance is uniform arithmetic)
  const ushort* Ku = KF + (size_t)bh * 32 * 8 * 512;
  const ushort* Vu = VF + (size_t)bh * 32 * 8 * 512;
  const ushort* Bu = BF + (size_t)(b * 64 + qtile) * 32 * 2048;
  const int koff = lane * 8;     // elements
  const int boff = lane * 16;    // fp16 elements

  float lr = 0.f;
  f32x16 o0, o1;
#pragma unroll
  for (int r = 0; r < 16; ++r) { o0[r] = 0.f; o1[r] = 0.f; }

  const int CROW0[16] = {0,1,2,3, 8,9,10,11, 16,17,18,19, 24,25,26,27};

  auto LOADK = [&](bf8 (&kf)[4][2], int t) {
    const ushort* p = Ku + (size_t)t * 4096 + koff;
#pragma unroll
    for (int ks = 0; ks < 4; ++ks) {
      kf[ks][0] = *(const bf8*)(p + (ks * 2 + 0) * 512);
      kf[ks][1] = *(const bf8*)(p + (ks * 2 + 1) * 512);
    }
  };
  auto LOADV = [&](bf8 (&vf)[4][2], int t) {
    const ushort* p = Vu + (size_t)t * 4096 + koff;
#pragma unroll
    for (int ks = 0; ks < 4; ++ks) {
      vf[ks][0] = *(const bf8*)(p + (ks * 2 + 0) * 512);
      vf[ks][1] = *(const bf8*)(p + (ks * 2 + 1) * 512);
    }
  };
  auto LOADB = [&](us8 (&bb)[4], int t) {       // 4 x 16B fp16 loads
    const ushort* p = Bu + (size_t)t * 2048 + boff;
    bb[0] = *(const us8*)(p);
    bb[1] = *(const us8*)(p + 8);
    bb[2] = *(const us8*)(p + 1024);
    bb[3] = *(const us8*)(p + 1024 + 8);
  };

  auto TILE = [&](const bf8 (&kf)[4][2], const bf8 (&vf)[4][2], const us8 (&bb)[4]) {
    // scores init = bias (fp16 -> f32 cvt straight into the accumulator)
    f32x16 s0, s1;
#pragma unroll
    for (int g = 0; g < 4; ++g)
#pragma unroll
      for (int j = 0; j < 4; ++j) {
        s0[g * 4 + j] = h2f(bb[g >> 1][(g & 1) * 4 + j]);
        s1[g * 4 + j] = h2f(bb[2 + (g >> 1)][(g & 1) * 4 + j]);
      }
    __builtin_amdgcn_s_setprio(1);
#pragma unroll
    for (int ks = 0; ks < 4; ++ks) {
      s0 = __builtin_amdgcn_mfma_f32_32x32x16_bf16(kf[ks][0], aq[ks], s0, 0, 0, 0);
      s1 = __builtin_amdgcn_mfma_f32_32x32x16_bf16(kf[ks][1], aq[ks], s1, 0, 0, 0);
    }
    __builtin_amdgcn_s_setprio(0);

    // softmax numerator: P = exp2(s) via raw v_exp_f32 builtin; sum lane-locally
#pragma unroll
    for (int r = 0; r < 16; ++r) {
      s0[r] = exp2raw(s0[r]);
      s1[r] = exp2raw(s1[r]);
    }
    float a8[8];
#pragma unroll
    for (int r = 0; r < 8; ++r)
      a8[r] = (s0[r] + s0[r + 8]) + (s1[r] + s1[r + 8]);
    lr += ((a8[0] + a8[4]) + (a8[1] + a8[5])) + ((a8[2] + a8[6]) + (a8[3] + a8[7]));

    // P (f32, S^T layout) -> PV A-fragments via cvt_pk + partner exchange
    bf8 pa[4];
#pragma unroll
    for (int t = 0; t < 2; ++t) {
      uint32_t wv[4][2];
#pragma unroll
      for (int g = 0; g < 4; ++g) {
        const float* sp = (t == 0) ? (const float*)&s0 : (const float*)&s1;
        wv[g][0] = cvtpk(sp[g * 4 + 0], sp[g * 4 + 1]);
        wv[g][1] = cvtpk(sp[g * 4 + 2], sp[g * 4 + 3]);
      }
#pragma unroll
      for (int pr = 0; pr < 2; ++pr) {
        uint32_t x0 = hi ? wv[2 * pr][0] : wv[2 * pr + 1][0];
        uint32_t x1 = hi ? wv[2 * pr][1] : wv[2 * pr + 1][1];
        uint32_t r0 = (uint32_t)__shfl_xor((int)x0, 32);
        uint32_t r1 = (uint32_t)__shfl_xor((int)x1, 32);
        uint4 pw;
        pw.x = hi ? r0 : wv[2 * pr][0];
        pw.y = hi ? r1 : wv[2 * pr][1];
        pw.z = hi ? wv[2 * pr + 1][0] : r0;
        pw.w = hi ? wv[2 * pr + 1][1] : r1;
        pa[t * 2 + pr] = __builtin_bit_cast(bf8, pw);
      }
    }

    __builtin_amdgcn_s_setprio(1);
#pragma unroll
    for (int ks = 0; ks < 4; ++ks) {
      o0 = __builtin_amdgcn_mfma_f32_32x32x16_bf16(pa[ks], vf[ks][0], o0, 0, 0, 0);
      o1 = __builtin_amdgcn_mfma_f32_32x32x16_bf16(pa[ks], vf[ks][1], o1, 0, 0, 0);
    }
    __builtin_amdgcn_s_setprio(0);
  };

  bf8 kA[4][2], kB[4][2], vC[4][2];
  us8 bA[4], bB[4];
  LOADK(kA, 0); LOADB(bA, 0);

#pragma unroll 1
  for (int p = 0; p < 15; ++p) {          // tiles 0..29 (steady)
    int t = 2 * p;
    LOADK(kB, t + 1); LOADB(bB, t + 1); LOADV(vC, t);
    TILE(kA, vC, bA);
    LOADK(kA, t + 2); LOADB(bA, t + 2); LOADV(vC, t + 1);
    TILE(kB, vC, bB);
  }
  // tiles 30, 31
  LOADK(kB, 31); LOADB(bB, 31); LOADV(vC, 30);
  TILE(kA, vC, bA);
  LOADV(vC, 31);
  TILE(kB, vC, bB);

  // combine the two kv halves of l once, then normalize
  lr += __shfl_xor(lr, 32);
  float inv = 1.0f / lr;
#pragma unroll
  for (int r = 0; r < 16; ++r) {
    float ivr = __shfl(inv, CROW0[r] + 4 * hi);
    int q = qtile * 32 + CROW0[r] + 4 * hi;
    size_t base = ((size_t)b * S_N + q) * D_N + h * 64 + l31;
    AO[base]      = f2b(o0[r] * ivr);
    AO[base + 32] = f2b(o1[r] * ivr);
  }
}

extern "C" void kernel_launch(void* const* d_in, const int* in_sizes, int n_in,
                              void* d_out, int out_size, void* d_ws, size_t ws_size,
                              hipStream_t stream) {
  (void)in_sizes; (void)n_in; (void)out_size; (void)ws_size;
  const float* query = (const float*)d_in[0];
  const float* key_  = (const float*)d_in[1];
  const float* value = (const float*)d_in[2];
  const int* fid  = (const int*)d_in[3];
  const int* eid  = (const int*)d_in[4];
  const int* tmid = (const int*)d_in[5];
  const int* ttid = (const int*)d_in[6];
  const int* edid = (const int*)d_in[7];
  const int* rlid = (const int*)d_in[8];
  const float* Wq = (const float*)d_in[9];  const float* bq = (const float*)d_in[10];
  const float* Wk = (const float*)d_in[11]; const float* bk = (const float*)d_in[12];
  const float* Wv = (const float*)d_in[13]; const float* bv = (const float*)d_in[14];
  const float* Wo = (const float*)d_in[15]; const float* bo = (const float*)d_in[16];

  char* ws = (char*)d_ws;
  const size_t MB = 1024 * 1024;
  // Projection phase: Xq 0-8, Xk 8-16, Xv 16-24, Wqb 24-26, Wkb 26-28, Wvb 28-30 (MB).
  // After gemm_qkv those are dead; BF fp16 (16.8MB) overwrites [0,17).
  ushort* Xq  = (ushort*)(ws);
  ushort* Xk  = (ushort*)(ws + 8 * MB);
  ushort* Xv  = (ushort*)(ws + 16 * MB);
  ushort* Wqb = (ushort*)(ws + 24 * MB);
  ushort* Wkb = (ushort*)(ws + 26 * MB);
  ushort* Wvb = (ushort*)(ws + 28 * MB);
  ushort* BF  = (ushort*)(ws);                      // fragment-major fp16 bias
  ushort* QFw = (ushort*)(ws + 30 * MB);
  ushort* KFw = (ushort*)(ws + 38 * MB);
  ushort* VFw = (ushort*)(ws + 46 * MB);
  ushort* AOw = (ushort*)(ws + 54 * MB);
  ushort* Wob = (ushort*)(ws + 62 * MB);
  uint32_t* codes = (uint32_t*)(ws + 64 * MB);
  // total ws use: 64MB + 16KB

  prep_kernel<<<16400, 256, 0, stream>>>(query, key_, value, Wq, Wk, Wv, Wo,
                                         Xq, Xk, Xv, Wqb, Wkb, Wvb, Wob,
                                         fid, eid, tmid, ttid, edid, rlid, codes);
  gemm_qkv<<<dim3(D_N / 128, (B_N * S_N) / 128, 3), 256, 0, stream>>>(
      Xq, Xk, Xv, Wqb, Wkb, Wvb, bq, bk, bv, QFw, KFw, VFw);
  // bias matrix overwrites Xq/Xk/start-of-Xv region (dead after gemm_qkv)
  bias_build<<<4096, 256, 0, stream>>>(codes, BF);
  attn_kernel<<<512, 256, 0, stream>>>(QFw, KFw, VFw, BF, AOw);
  gemm_o<<<dim3(D_N / 128, (B_N * S_N) / 64), 256, 0, stream>>>(AOw, Wob, bo, (float*)d_out);
}